// Round 4
// baseline (186.197 us; speedup 1.0000x reference)
//
#include <hip/hip_runtime.h>

#define N_NODES 50000
#define N_EDGES 300000
#define D_FEAT 256
// Live computation (sage1/sage2 outputs are dead in the reference):
// h = relu(mean_agg(x)@Wl3 + x@Wr3 + b3)
// out = log_softmax(mean_agg(h)@Wl4 + h@Wr4 + b4)
// Projection commutes with mean -> project first (256->32 via MFMA), then
// aggregate in 32-dim space via CSR-build + gather (no f32 atomics, no
// agg zero-init). 8 kernels total.

typedef __attribute__((ext_vector_type(8))) short bf16x8;
typedef __attribute__((ext_vector_type(4))) float f32x4;

__device__ __forceinline__ unsigned short f2bf(float f) {
    unsigned int u = __builtin_bit_cast(unsigned int, f);
    u += 0x7fffu + ((u >> 16) & 1u);   // round-to-nearest-even
    return (unsigned short)(u >> 16);
}

// K1: zero hist + pack [Wl3|Wr3] into bf16 B-fragment order.
// bp[((nt*8+ks)*64+lane)*8 + j] = W(k = ks*32+(lane>>4)*8+j, c = nt*16+(lane&15))
__global__ __launch_bounds__(256) void init_kernel(const float* __restrict__ Wl,
        const float* __restrict__ Wr, unsigned short* __restrict__ bp,
        int* __restrict__ hist) {
    int g = blockIdx.x * 256 + threadIdx.x;
    if (g < N_NODES) hist[g] = 0;
    if (g < 2048) {
        int lane = g & 63;
        int ks = (g >> 6) & 7;
        int nt = g >> 9;
        int c = nt * 16 + (lane & 15);
        int kbase = ks * 32 + (lane >> 4) * 8;
        unsigned short o[8];
#pragma unroll
        for (int j = 0; j < 8; ++j) {
            int k = kbase + j;
            float v = (c < 32) ? Wl[k * 32 + c] : Wr[k * 32 + (c - 32)];
            o[j] = f2bf(v);
        }
        uint4 pk;
        pk.x = (unsigned)o[0] | ((unsigned)o[1] << 16);
        pk.y = (unsigned)o[2] | ((unsigned)o[3] << 16);
        pk.z = (unsigned)o[4] | ((unsigned)o[5] << 16);
        pk.w = (unsigned)o[6] | ((unsigned)o[7] << 16);
        ((uint4*)bp)[g] = pk;
    }
}

// K2: in-degree histogram
__global__ __launch_bounds__(256) void hist_kernel(const int* __restrict__ ei,
                                                   int* __restrict__ hist) {
    int e = blockIdx.x * 256 + threadIdx.x;
    if (e < N_EDGES) atomicAdd(&hist[ei[N_EDGES + e]], 1);
}

// K3: single-block exclusive scan of hist -> rowptr, cursor (1024 thr, 49 elem/thr)
#define CHUNK 49
__global__ __launch_bounds__(1024) void scan_kernel(const int* __restrict__ hist,
        int* __restrict__ rowptr, int* __restrict__ cursor) {
    __shared__ int s[1024];
    const int t = threadIdx.x;
    const int base = t * CHUNK;
    int loc[CHUNK];
    int sum = 0;
#pragma unroll
    for (int j = 0; j < CHUNK; ++j) {
        int idx = base + j;
        int v = (idx < N_NODES) ? hist[idx] : 0;
        loc[j] = v;
        sum += v;
    }
    s[t] = sum;
    __syncthreads();
    int acc = sum;
    for (int off = 1; off < 1024; off <<= 1) {
        int add = (t >= off) ? s[t - off] : 0;
        __syncthreads();
        acc += add;
        s[t] = acc;
        __syncthreads();
    }
    int run = acc - sum;   // exclusive prefix of this thread's chunk
#pragma unroll
    for (int j = 0; j < CHUNK; ++j) {
        int idx = base + j;
        if (idx < N_NODES) { rowptr[idx] = run; cursor[idx] = run; }
        run += loc[j];
    }
    if (t == 0) rowptr[N_NODES] = N_EDGES;
}

// K4: scatter edges into CSR via per-node cursors
__global__ __launch_bounds__(256) void fill_kernel(const int* __restrict__ ei,
        int* __restrict__ cursor, int* __restrict__ csr) {
    int e = blockIdx.x * 256 + threadIdx.x;
    if (e < N_EDGES) {
        int d = ei[N_EDGES + e];
        int pos = atomicAdd(&cursor[d], 1);
        csr[pos] = ei[e];
    }
}

// K5: xl = x @ Wl3, xr = x @ Wr3 via bf16 MFMA; 4 waves/block, 16 rows/wave.
__global__ __launch_bounds__(256) void proj3_mfma(const float* __restrict__ x,
        const unsigned short* __restrict__ bp,
        float* __restrict__ xl, float* __restrict__ xr) {
    const int lane = threadIdx.x & 63;
    const int wv = threadIdx.x >> 6;
    const int row0 = blockIdx.x * 64 + wv * 16;
    const int arow = row0 + (lane & 15);
    const int kq = lane >> 4;
    const bool valid = arow < N_NODES;

    bf16x8 a[8];
    const float* xp = x + (size_t)arow * D_FEAT + kq * 8;
#pragma unroll
    for (int ks = 0; ks < 8; ++ks) {
        float4 p0, p1;
        if (valid) {
            p0 = *(const float4*)(xp + ks * 32);
            p1 = *(const float4*)(xp + ks * 32 + 4);
        } else {
            p0 = make_float4(0.f, 0.f, 0.f, 0.f);
            p1 = p0;
        }
        bf16x8 av;
        av[0] = (short)f2bf(p0.x); av[1] = (short)f2bf(p0.y);
        av[2] = (short)f2bf(p0.z); av[3] = (short)f2bf(p0.w);
        av[4] = (short)f2bf(p1.x); av[5] = (short)f2bf(p1.y);
        av[6] = (short)f2bf(p1.z); av[7] = (short)f2bf(p1.w);
        a[ks] = av;
    }

    f32x4 acc[4];
#pragma unroll
    for (int nt = 0; nt < 4; ++nt) acc[nt] = (f32x4){0.f, 0.f, 0.f, 0.f};

    const uint4* bq = (const uint4*)bp;
#pragma unroll
    for (int nt = 0; nt < 4; ++nt) {
#pragma unroll
        for (int ks = 0; ks < 8; ++ks) {
            bf16x8 b = __builtin_bit_cast(bf16x8, bq[(nt * 8 + ks) * 64 + lane]);
            acc[nt] = __builtin_amdgcn_mfma_f32_16x16x32_bf16(a[ks], b, acc[nt], 0, 0, 0);
        }
    }

    // C/D: col = lane&15, row = (lane>>4)*4 + reg
    const int orow = row0 + (lane >> 4) * 4;
    const int ocol = lane & 15;
#pragma unroll
    for (int nt = 0; nt < 4; ++nt) {
        float* dst = (nt < 2) ? xl : xr;
        const int cc = (nt & 1) * 16 + ocol;
#pragma unroll
        for (int i = 0; i < 4; ++i) {
            int r = orow + i;
            if (r < N_NODES) dst[(size_t)r * 32 + cc] = acc[nt][i];
        }
    }
}

// K6: h[n][c] = relu( (sum_{src} xl[src][c]) / deg + xr[n][c] + b3[c] )
// 32 lanes per node, 2-way edge unroll for ILP.
__global__ __launch_bounds__(256) void h_gather(const int* __restrict__ rowptr,
        const int* __restrict__ csr, const float* __restrict__ xl,
        const float* __restrict__ xr, const float* __restrict__ b3,
        float* __restrict__ h) {
    int gid = blockIdx.x * 256 + threadIdx.x;
    int n = gid >> 5, c = gid & 31;
    if (n >= N_NODES) return;
    const int beg = rowptr[n], end = rowptr[n + 1];
    float sum = 0.0f;
    int i = beg;
    for (; i + 2 <= end; i += 2) {
        int s0 = csr[i];
        int s1 = csr[i + 1];
        float v0 = xl[(size_t)s0 * 32 + c];
        float v1 = xl[(size_t)s1 * 32 + c];
        sum += v0 + v1;
    }
    if (i < end) sum += xl[(size_t)csr[i] * 32 + c];
    float inv = 1.0f / (float)max(end - beg, 1);
    h[gid] = fmaxf(fmaf(sum, inv, xr[gid] + b3[c]), 0.0f);
}

// K7: m4[n][c] = (sum_{src} h[src][c]) / deg
__global__ __launch_bounds__(256) void m4_gather(const int* __restrict__ rowptr,
        const int* __restrict__ csr, const float* __restrict__ h,
        float* __restrict__ m4) {
    int gid = blockIdx.x * 256 + threadIdx.x;
    int n = gid >> 5, c = gid & 31;
    if (n >= N_NODES) return;
    const int beg = rowptr[n], end = rowptr[n + 1];
    float sum = 0.0f;
    int i = beg;
    for (; i + 2 <= end; i += 2) {
        int s0 = csr[i];
        int s1 = csr[i + 1];
        float v0 = h[(size_t)s0 * 32 + c];
        float v1 = h[(size_t)s1 * 32 + c];
        sum += v0 + v1;
    }
    if (i < end) sum += h[(size_t)csr[i] * 32 + c];
    m4[gid] = sum / (float)max(end - beg, 1);
}

// K8: out = log_softmax(m4 @ Wl4 + h @ Wr4 + b4); 8 lanes/node x 5 cols.
__global__ __launch_bounds__(256) void out8_kernel(const float* __restrict__ m4,
        const float* __restrict__ h, const float* __restrict__ Wl4,
        const float* __restrict__ Wr4, const float* __restrict__ b4,
        float* __restrict__ out) {
    __shared__ float w[32][80];
    const int tid = threadIdx.x;
    for (int i = tid; i < 32 * 80; i += 256) {
        int k = i / 80, c = i - k * 80;
        w[k][c] = (c < 40) ? Wl4[k * 40 + c] : Wr4[k * 40 + (c - 40)];
    }
    __syncthreads();
    const int gid = blockIdx.x * 256 + tid;
    const int node = gid >> 3, q = gid & 7;
    if (node >= N_NODES) return;
    const int c0 = q * 5;
    float acc[5];
#pragma unroll
    for (int c = 0; c < 5; ++c) acc[c] = b4[c0 + c];
    const float* mp = m4 + (size_t)node * 32;
    const float* hp = h + (size_t)node * 32;
#pragma unroll 8
    for (int k = 0; k < 32; ++k) {
        float mv = mp[k];
        float hv = hp[k];
#pragma unroll
        for (int c = 0; c < 5; ++c)
            acc[c] += mv * w[k][c0 + c] + hv * w[k][40 + c0 + c];
    }
    float m = acc[0];
#pragma unroll
    for (int c = 1; c < 5; ++c) m = fmaxf(m, acc[c]);
#pragma unroll
    for (int off = 1; off < 8; off <<= 1) m = fmaxf(m, __shfl_xor(m, off, 8));
    float s = 0.0f;
#pragma unroll
    for (int c = 0; c < 5; ++c) s += expf(acc[c] - m);
#pragma unroll
    for (int off = 1; off < 8; off <<= 1) s += __shfl_xor(s, off, 8);
    const float ls = logf(s) + m;
    float* op = out + (size_t)node * 40 + c0;
#pragma unroll
    for (int c = 0; c < 5; ++c) op[c] = acc[c] - ls;
}

extern "C" void kernel_launch(void* const* d_in, const int* in_sizes, int n_in,
                              void* d_out, int out_size, void* d_ws, size_t ws_size,
                              hipStream_t stream) {
    const float* x   = (const float*)d_in[0];
    const int*   ei  = (const int*)d_in[1];
    const float* Wl3 = (const float*)d_in[8];
    const float* Wr3 = (const float*)d_in[9];
    const float* b3  = (const float*)d_in[10];
    const float* Wl4 = (const float*)d_in[11];
    const float* Wr4 = (const float*)d_in[12];
    const float* b4  = (const float*)d_in[13];
    float* outf = (float*)d_out;

    const int NB_NODES = (N_NODES + 255) / 256;   // 196
    const int NB_EDGES = (N_EDGES + 255) / 256;   // 1172

    char* p = (char*)d_ws;
    int* hist    = (int*)p;            p += sizeof(int) * N_NODES;
    int* rowptr  = (int*)p;            p += sizeof(int) * (N_NODES + 1);
    int* cursor  = (int*)p;            p += sizeof(int) * N_NODES;
    int* csr     = (int*)p;            p += sizeof(int) * N_EDGES;
    float* xl    = (float*)p;          p += sizeof(float) * (size_t)N_NODES * 32;
    float* xr    = (float*)p;          p += sizeof(float) * (size_t)N_NODES * 32;
    float* h     = (float*)p;          p += sizeof(float) * (size_t)N_NODES * 32;
    float* m4    = (float*)p;          p += sizeof(float) * (size_t)N_NODES * 32;
    unsigned short* bpack = (unsigned short*)p;   // 16384 ushorts

    init_kernel<<<NB_NODES, 256, 0, stream>>>(Wl3, Wr3, bpack, hist);
    hist_kernel<<<NB_EDGES, 256, 0, stream>>>(ei, hist);
    scan_kernel<<<1, 1024, 0, stream>>>(hist, rowptr, cursor);
    fill_kernel<<<NB_EDGES, 256, 0, stream>>>(ei, cursor, csr);
    proj3_mfma<<<(N_NODES + 63) / 64, 256, 0, stream>>>(x, bpack, xl, xr);
    h_gather<<<(N_NODES * 32 + 255) / 256, 256, 0, stream>>>(rowptr, csr, xl, xr, b3, h);
    m4_gather<<<(N_NODES * 32 + 255) / 256, 256, 0, stream>>>(rowptr, csr, h, m4);
    out8_kernel<<<(N_NODES * 8 + 255) / 256, 256, 0, stream>>>(m4, h, Wl4, Wr4, b4, outf);
}

// Round 5
// 127.746 us; speedup vs baseline: 1.4576x; 1.4576x over previous
//
#include <hip/hip_runtime.h>

#define N_NODES 50000
#define N_EDGES 300000
#define D_FEAT 256
// Live computation (sage1/sage2 outputs are dead in the reference):
// h = relu(mean_agg(x)@Wl3 + x@Wr3 + b3)
// out = log_softmax(mean_agg(h)@Wl4 + h@Wr4 + b4)
// Project first (256->32 via bf16 MFMA), aggregate in 32-dim space via
// CSR-build + gather. 7 kernels.

typedef __attribute__((ext_vector_type(8))) short bf16x8;
typedef __attribute__((ext_vector_type(4))) float f32x4;

__device__ __forceinline__ unsigned short f2bf(float f) {
    unsigned int u = __builtin_bit_cast(unsigned int, f);
    u += 0x7fffu + ((u >> 16) & 1u);   // round-to-nearest-even
    return (unsigned short)(u >> 16);
}

// pack two f32 -> one dword of 2 bf16 (RNE), low = lo, high = hi
__device__ __forceinline__ unsigned cvt2bf(float lo, float hi) {
    unsigned r;
    asm("v_cvt_pk_bf16_f32 %0, %1, %2" : "=v"(r) : "v"(lo), "v"(hi));
    return r;
}

// K1: zero hist + pack [Wl3|Wr3] into bf16 B-fragment order.
// bp[((nt*8+ks)*64+lane)*8 + j] = W(k = ks*32+(lane>>4)*8+j, c = nt*16+(lane&15))
__global__ __launch_bounds__(256) void init_kernel(const float* __restrict__ Wl,
        const float* __restrict__ Wr, unsigned short* __restrict__ bp,
        int* __restrict__ hist) {
    int g = blockIdx.x * 256 + threadIdx.x;
    if (g < N_NODES) hist[g] = 0;
    if (g < 2048) {
        int lane = g & 63;
        int ks = (g >> 6) & 7;
        int nt = g >> 9;
        int c = nt * 16 + (lane & 15);
        int kbase = ks * 32 + (lane >> 4) * 8;
        unsigned short o[8];
#pragma unroll
        for (int j = 0; j < 8; ++j) {
            int k = kbase + j;
            float v = (c < 32) ? Wl[k * 32 + c] : Wr[k * 32 + (c - 32)];
            o[j] = f2bf(v);
        }
        uint4 pk;
        pk.x = (unsigned)o[0] | ((unsigned)o[1] << 16);
        pk.y = (unsigned)o[2] | ((unsigned)o[3] << 16);
        pk.z = (unsigned)o[4] | ((unsigned)o[5] << 16);
        pk.w = (unsigned)o[6] | ((unsigned)o[7] << 16);
        ((uint4*)bp)[g] = pk;
    }
}

// K2: in-degree histogram
__global__ __launch_bounds__(256) void hist_kernel(const int* __restrict__ ei,
                                                   int* __restrict__ hist) {
    int e = blockIdx.x * 256 + threadIdx.x;
    if (e < N_EDGES) atomicAdd(&hist[ei[N_EDGES + e]], 1);
}

// K3: single-block exclusive scan, int4 tiles, registers only (no spill).
__global__ __launch_bounds__(1024) void scan_kernel(const int* __restrict__ hist,
        int* __restrict__ rowptr, int* __restrict__ cursor) {
    __shared__ int wsum[16];
    const int t = threadIdx.x;
    const int lane = t & 63, wid = t >> 6;
    int running = 0;
    const int NTILE = (N_NODES + 4095) / 4096;   // 13
    for (int tile = 0; tile < NTILE; ++tile) {
        const int base = tile * 4096 + t * 4;
        int4 v;
        if (base + 3 < N_NODES) {
            v = *(const int4*)(hist + base);
        } else {
            v.x = (base + 0 < N_NODES) ? hist[base + 0] : 0;
            v.y = (base + 1 < N_NODES) ? hist[base + 1] : 0;
            v.z = (base + 2 < N_NODES) ? hist[base + 2] : 0;
            v.w = (base + 3 < N_NODES) ? hist[base + 3] : 0;
        }
        const int s = v.x + v.y + v.z + v.w;
        int sc = s;                      // inclusive scan over 64 lanes
#pragma unroll
        for (int off = 1; off < 64; off <<= 1) {
            int u = __shfl_up(sc, off, 64);
            if (lane >= off) sc += u;
        }
        if (lane == 63) wsum[wid] = sc;
        __syncthreads();
        if (t < 16) {                    // scan the 16 wave totals
            int ps = wsum[t];
#pragma unroll
            for (int off = 1; off < 16; off <<= 1) {
                int u = __shfl_up(ps, off, 64);
                if (t >= off) ps += u;
            }
            wsum[t] = ps;                // inclusive
        }
        __syncthreads();
        const int waveoff = (wid > 0) ? wsum[wid - 1] : 0;
        const int tiletotal = wsum[15];
        int excl = running + waveoff + (sc - s);
        if (base + 3 < N_NODES) {
            int4 r;
            r.x = excl;
            r.y = excl + v.x;
            r.z = excl + v.x + v.y;
            r.w = excl + v.x + v.y + v.z;
            *(int4*)(rowptr + base) = r;
            *(int4*)(cursor + base) = r;
        } else {
            int run2 = excl;
            if (base + 0 < N_NODES) { rowptr[base + 0] = run2; cursor[base + 0] = run2; run2 += v.x; }
            if (base + 1 < N_NODES) { rowptr[base + 1] = run2; cursor[base + 1] = run2; run2 += v.y; }
            if (base + 2 < N_NODES) { rowptr[base + 2] = run2; cursor[base + 2] = run2; run2 += v.z; }
            if (base + 3 < N_NODES) { rowptr[base + 3] = run2; cursor[base + 3] = run2; }
        }
        running += tiletotal;
        __syncthreads();                 // wsum reused next tile
    }
    if (t == 0) rowptr[N_NODES] = N_EDGES;
}

// K4: scatter edges into CSR via per-node cursors
__global__ __launch_bounds__(256) void fill_kernel(const int* __restrict__ ei,
        int* __restrict__ cursor, int* __restrict__ csr) {
    int e = blockIdx.x * 256 + threadIdx.x;
    if (e < N_EDGES) {
        int d = ei[N_EDGES + e];
        int pos = atomicAdd(&cursor[d], 1);
        csr[pos] = ei[e];
    }
}

// K5: xl = x @ Wl3, xr = x @ Wr3 via bf16 MFMA; 4 waves/block, 16 rows/wave.
__global__ __launch_bounds__(256) void proj3_mfma(const float* __restrict__ x,
        const unsigned short* __restrict__ bp,
        float* __restrict__ xl, float* __restrict__ xr) {
    const int lane = threadIdx.x & 63;
    const int wv = threadIdx.x >> 6;
    const int row0 = blockIdx.x * 64 + wv * 16;
    const int arow = row0 + (lane & 15);
    const int kq = lane >> 4;
    const bool valid = arow < N_NODES;

    bf16x8 a[8];
    const float* xp = x + (size_t)arow * D_FEAT + kq * 8;
#pragma unroll
    for (int ks = 0; ks < 8; ++ks) {
        float4 p0, p1;
        if (valid) {
            p0 = *(const float4*)(xp + ks * 32);
            p1 = *(const float4*)(xp + ks * 32 + 4);
        } else {
            p0 = make_float4(0.f, 0.f, 0.f, 0.f);
            p1 = p0;
        }
        uint4 au;
        au.x = cvt2bf(p0.x, p0.y);
        au.y = cvt2bf(p0.z, p0.w);
        au.z = cvt2bf(p1.x, p1.y);
        au.w = cvt2bf(p1.z, p1.w);
        a[ks] = __builtin_bit_cast(bf16x8, au);
    }

    f32x4 acc[4];
#pragma unroll
    for (int nt = 0; nt < 4; ++nt) acc[nt] = (f32x4){0.f, 0.f, 0.f, 0.f};

    const uint4* bq = (const uint4*)bp;
#pragma unroll
    for (int nt = 0; nt < 4; ++nt) {
#pragma unroll
        for (int ks = 0; ks < 8; ++ks) {
            bf16x8 b = __builtin_bit_cast(bf16x8, bq[(nt * 8 + ks) * 64 + lane]);
            acc[nt] = __builtin_amdgcn_mfma_f32_16x16x32_bf16(a[ks], b, acc[nt], 0, 0, 0);
        }
    }

    // C/D: col = lane&15, row = (lane>>4)*4 + reg
    const int orow = row0 + (lane >> 4) * 4;
    const int ocol = lane & 15;
#pragma unroll
    for (int nt = 0; nt < 4; ++nt) {
        float* dst = (nt < 2) ? xl : xr;
        const int cc = (nt & 1) * 16 + ocol;
#pragma unroll
        for (int i = 0; i < 4; ++i) {
            int r = orow + i;
            if (r < N_NODES) dst[(size_t)r * 32 + cc] = acc[nt][i];
        }
    }
}

// K6: h[n][c] = relu( (sum_{src} xl[src][c]) / deg + xr[n][c] + b3[c] )
__global__ __launch_bounds__(256) void h_gather(const int* __restrict__ rowptr,
        const int* __restrict__ csr, const float* __restrict__ xl,
        const float* __restrict__ xr, const float* __restrict__ b3,
        float* __restrict__ h) {
    int gid = blockIdx.x * 256 + threadIdx.x;
    int n = gid >> 5, c = gid & 31;
    if (n >= N_NODES) return;
    const int beg = rowptr[n], end = rowptr[n + 1];
    float sum = 0.0f;
    int i = beg;
    for (; i + 4 <= end; i += 4) {
        int s0 = csr[i], s1 = csr[i + 1], s2 = csr[i + 2], s3 = csr[i + 3];
        float v0 = xl[(size_t)s0 * 32 + c];
        float v1 = xl[(size_t)s1 * 32 + c];
        float v2 = xl[(size_t)s2 * 32 + c];
        float v3 = xl[(size_t)s3 * 32 + c];
        sum += (v0 + v1) + (v2 + v3);
    }
    for (; i < end; ++i) sum += xl[(size_t)csr[i] * 32 + c];
    float inv = 1.0f / (float)max(end - beg, 1);
    h[gid] = fmaxf(fmaf(sum, inv, xr[gid] + b3[c]), 0.0f);
}

// K7: fused m4-gather + output layer + log_softmax.
// Half-wave (32 lanes) per node; 8 nodes per 256-thread block.
__global__ __launch_bounds__(256) void m4out_kernel(const int* __restrict__ rowptr,
        const int* __restrict__ csr, const float* __restrict__ h,
        const float* __restrict__ Wl4, const float* __restrict__ Wr4,
        const float* __restrict__ b4, float* __restrict__ out) {
    __shared__ float w[32][80];
    __shared__ float m4s[8][32];
    __shared__ float hs[8][32];
    const int tid = threadIdx.x;
    for (int i = tid; i < 32 * 80; i += 256) {
        int k = i / 80, c = i - k * 80;
        w[k][c] = (c < 40) ? Wl4[k * 40 + c] : Wr4[k * 40 + (c - 40)];
    }
    const int hw = tid >> 5;
    const int c = tid & 31;
    const int node = blockIdx.x * 8 + hw;
    float mv = 0.0f, hv = 0.0f;
    if (node < N_NODES) {
        const int beg = rowptr[node], end = rowptr[node + 1];
        float sum = 0.0f;
        int i = beg;
        for (; i + 4 <= end; i += 4) {
            int s0 = csr[i], s1 = csr[i + 1], s2 = csr[i + 2], s3 = csr[i + 3];
            float v0 = h[(size_t)s0 * 32 + c];
            float v1 = h[(size_t)s1 * 32 + c];
            float v2 = h[(size_t)s2 * 32 + c];
            float v3 = h[(size_t)s3 * 32 + c];
            sum += (v0 + v1) + (v2 + v3);
        }
        for (; i < end; ++i) sum += h[(size_t)csr[i] * 32 + c];
        mv = sum / (float)max(end - beg, 1);
        hv = h[(size_t)node * 32 + c];
    }
    m4s[hw][c] = mv;
    hs[hw][c] = hv;
    __syncthreads();
    if (node >= N_NODES) return;
    const bool act = (c < 20);
    float acc0 = act ? b4[c] : 0.0f;
    float acc1 = act ? b4[c + 20] : 0.0f;
#pragma unroll 8
    for (int k = 0; k < 32; ++k) {
        float mk = m4s[hw][k];
        float hk = hs[hw][k];
        acc0 += mk * w[k][c] + hk * w[k][40 + c];
        acc1 += mk * w[k][c + 20] + hk * w[k][60 + c];
    }
    float m = act ? fmaxf(acc0, acc1) : -INFINITY;
#pragma unroll
    for (int off = 1; off < 32; off <<= 1) m = fmaxf(m, __shfl_xor(m, off, 32));
    float e = act ? (expf(acc0 - m) + expf(acc1 - m)) : 0.0f;
#pragma unroll
    for (int off = 1; off < 32; off <<= 1) e += __shfl_xor(e, off, 32);
    const float ls = logf(e) + m;
    if (act) {
        out[(size_t)node * 40 + c] = acc0 - ls;
        out[(size_t)node * 40 + c + 20] = acc1 - ls;
    }
}

extern "C" void kernel_launch(void* const* d_in, const int* in_sizes, int n_in,
                              void* d_out, int out_size, void* d_ws, size_t ws_size,
                              hipStream_t stream) {
    const float* x   = (const float*)d_in[0];
    const int*   ei  = (const int*)d_in[1];
    const float* Wl3 = (const float*)d_in[8];
    const float* Wr3 = (const float*)d_in[9];
    const float* b3  = (const float*)d_in[10];
    const float* Wl4 = (const float*)d_in[11];
    const float* Wr4 = (const float*)d_in[12];
    const float* b4  = (const float*)d_in[13];
    float* outf = (float*)d_out;

    const int NB_NODES = (N_NODES + 255) / 256;   // 196
    const int NB_EDGES = (N_EDGES + 255) / 256;   // 1172

    char* p = (char*)d_ws;
    int* hist    = (int*)p;            p += sizeof(int) * N_NODES;
    int* rowptr  = (int*)p;            p += sizeof(int) * (N_NODES + 4);  // pad keeps 16B alignment
    int* cursor  = (int*)p;            p += sizeof(int) * N_NODES;
    int* csr     = (int*)p;            p += sizeof(int) * N_EDGES;
    float* xl    = (float*)p;          p += sizeof(float) * (size_t)N_NODES * 32;
    float* xr    = (float*)p;          p += sizeof(float) * (size_t)N_NODES * 32;
    float* h     = (float*)p;          p += sizeof(float) * (size_t)N_NODES * 32;
    unsigned short* bpack = (unsigned short*)p;   // 16384 ushorts

    init_kernel<<<NB_NODES, 256, 0, stream>>>(Wl3, Wr3, bpack, hist);
    hist_kernel<<<NB_EDGES, 256, 0, stream>>>(ei, hist);
    scan_kernel<<<1, 1024, 0, stream>>>(hist, rowptr, cursor);
    fill_kernel<<<NB_EDGES, 256, 0, stream>>>(ei, cursor, csr);
    proj3_mfma<<<(N_NODES + 63) / 64, 256, 0, stream>>>(x, bpack, xl, xr);
    h_gather<<<(N_NODES * 32 + 255) / 256, 256, 0, stream>>>(rowptr, csr, xl, xr, b3, h);
    m4out_kernel<<<(N_NODES + 7) / 8, 256, 0, stream>>>(rowptr, csr, h, Wl4, Wr4, b4, outf);
}